// Round 7
// baseline (648.507 us; speedup 1.0000x reference)
//
#include <hip/hip_runtime.h>
#include <hip/hip_bf16.h>

// CliffordEPBottleneck: 10x { rho=tanh(h); drive=W_sym@rho+x; h=0.9h+0.1(1-rho^2)drive }
// Core: 10x GEMM (1024 x 4096 x 4096) bf16 MFMA.
//
// R7: split-K=2 -> grid 1024 = 4 blocks/CU = 16 waves/CU (R2-R6 were grid-capped
// at 2 blocks/CU; serial-sum of pipes ~= measured cycles -> need more wave
// stagger). W pre-packed in MFMA fragment order (conflict-free frag-major LDS,
// coalesced DMA source). A direct from packed P (R6-proven). bf16 partials +
// memory-bound combine kernel for the epilogue.

#define NODES 4096
#define KDIM  4096
#define MDIM  1024
#define DLEN  16384
#define BM 64
#define BN 128
#define BK 32
#define HALF_ELEMS 4194304   // MDIM*NODES (one partial plane)

typedef __attribute__((ext_vector_type(8))) __bf16 bf16x8;
typedef __attribute__((ext_vector_type(8))) unsigned short u16x8;
typedef __attribute__((ext_vector_type(4))) float  f32x4;

static __device__ __forceinline__ unsigned short f32_to_bf16(float f) {
    unsigned int u = __float_as_uint(f);
    u += 0x7fffu + ((u >> 16) & 1u);   // round-to-nearest-even
    return (unsigned short)(u >> 16);
}
static __device__ __forceinline__ float bf16_to_f32(unsigned short u) {
    return __uint_as_float(((unsigned int)u) << 16);
}

// ---------------------------------------------------------------------------
// Kernel 1: Wbp = bf16(0.5*(W+W^T)) packed in B-fragment order.
// Element (n, k) lives at:
//   ((k>>5)*256 + (n>>4))*512 + ((n&15) | (((k>>3)&3)<<4))*8 + (k&7)
// so fragment (t32=k>>5, nf=n>>4) is one contiguous 1 KB chunk:
// lane l supplies row n=nf*16+(l&15), k-elems (l>>4)*8+e  (MFMA B layout).
// ---------------------------------------------------------------------------
__global__ __launch_bounds__(256)
void symw_kernel(const float* __restrict__ W, unsigned short* __restrict__ Wbp) {
    __shared__ float Ta[64][64];
    __shared__ float Tb[64][65];
    const int tn = blockIdx.y, tm = blockIdx.x;
    const int c  = threadIdx.x & 63;
    const int r0 = threadIdx.x >> 6;
#pragma unroll
    for (int rr = 0; rr < 16; ++rr) {
        int r = r0 * 16 + rr;
        Ta[r][c] = W[(size_t)(tn * 64 + r) * 4096 + tm * 64 + c];
        Tb[r][c] = W[(size_t)(tm * 64 + r) * 4096 + tn * 64 + c];
    }
    __syncthreads();
#pragma unroll
    for (int rr = 0; rr < 16; ++rr) {
        int r = r0 * 16 + rr;
        float v = 0.5f * (Ta[r][c] + Tb[c][r]);
        int n = tn * 64 + r;
        int k = tm * 64 + c;
        size_t addr = ((size_t)(k >> 5) * 256 + (n >> 4)) * 512
                    + (size_t)((n & 15) | (((k >> 3) & 3) << 4)) * 8 + (k & 7);
        Wbp[addr] = f32_to_bf16(v);
    }
}

// ---------------------------------------------------------------------------
// Kernel 2: h = x ; P0 = packed bf16(tanh(x)) in A-fragment order.
// Element (i=b*4+c, k=m) at: (k>>5)*32768 + (i>>4)*512
//                            + ((i&15) | (((k>>3)&3)<<4))*8 + (k&7)
// ---------------------------------------------------------------------------
__global__ __launch_bounds__(256)
void init_kernel(const float* __restrict__ x, float* __restrict__ h,
                 unsigned short* __restrict__ P0) {
    int idx = blockIdx.x * blockDim.x + threadIdx.x;   // over B*NODES = 1M
    int b = idx >> 12;
    int m = idx & 4095;
    f32x4 xv = *(const f32x4*)(x + (size_t)idx * 4);
    *(f32x4*)(h + (size_t)idx * 4) = xv;
    size_t base = ((size_t)(m >> 5) * 64 + (b >> 2)) * 512
                + (size_t)((m >> 3) & 3) * 128 + (m & 7);
#pragma unroll
    for (int c = 0; c < 4; ++c) {
        P0[base + (size_t)((b & 3) * 4 + c) * 8] = f32_to_bf16(tanhf(xv[c]));
    }
}

// ---------------------------------------------------------------------------
// Kernel 3: split-K GEMM half. grid (32, 16, 2), 256 thr (4 waves).
// BM=64 BN=128 BK=32; wave = 32x64 (2x4 frags of 16x16x32).
// B: frag-packed ring-3 LDS via global_load_lds (conflict-free lane-linear).
// A: direct bf16x8 loads from packed P. Counted vmcnt(4), 1 barrier/tile.
// Output: bf16 partial Dp[ks][i][n].
// ---------------------------------------------------------------------------
__global__ __launch_bounds__(256, 4)
void gemm_kernel(const unsigned short* __restrict__ Pcur,
                 const unsigned short* __restrict__ Wbp,
                 unsigned short* __restrict__ Dp) {
    __shared__ unsigned short Bs[3][BN * BK];   // 3 x 8 KB, frag-major

    const int tid  = threadIdx.x;
    const int bx   = blockIdx.x;            // n-tile (0..31)
    const int by   = blockIdx.y;            // m-tile (0..15)
    const int ks   = blockIdx.z;            // K half (0..1)
    const int w    = tid >> 6;
    const int lane = tid & 63;
    const int lr   = lane & 15;
    const int lk   = lane >> 4;
    const int m0   = (w >> 1) * 32;
    const int n0   = (w & 1) * 64;
    const int mr0  = by * 4 + (m0 >> 4);     // global A-frag row base
    const int T0   = ks * 64;                // first k32-tile of this half

    // staging: 2 chunks/thread; chunk c covers LDS frag (c>>6), lane (c&63)
    size_t soff[2]; int dsto[2];
#pragma unroll
    for (int j = 0; j < 2; ++j) {
        int c = tid + 256 * j;               // 0..511
        soff[j] = ((size_t)(bx * 8 + (c >> 6))) * 512 + (size_t)(c & 63) * 8;
        dsto[j] = c * 8;
    }
    size_t aoff[2];
#pragma unroll
    for (int mi = 0; mi < 2; ++mi)
        aoff[mi] = (size_t)(mr0 + mi) * 512 + (size_t)lane * 8;
    const int boff = ((w & 1) * 4) * 512 + lane * 8;   // + ni*512 (+buf*4096)

    f32x4 acc[2][4];
#pragma unroll
    for (int mi = 0; mi < 2; ++mi)
#pragma unroll
        for (int ni = 0; ni < 4; ++ni)
            acc[mi][ni] = (f32x4){0.f, 0.f, 0.f, 0.f};

    unsigned short* BsF = &Bs[0][0];

#define STAGE(buf, t32)                                                         \
    do {                                                                        \
        _Pragma("unroll")                                                       \
        for (int j = 0; j < 2; ++j) {                                           \
            __builtin_amdgcn_global_load_lds(                                   \
                (const __attribute__((address_space(1))) void*)                \
                    (Wbp + (size_t)(t32) * 131072 + soff[j]),                   \
                (__attribute__((address_space(3))) void*)                      \
                    (BsF + (buf) * 4096 + dsto[j]),                             \
                16, 0, 0);                                                      \
        }                                                                       \
    } while (0)

#define LOADA(s, t32)                                                           \
    do {                                                                        \
        _Pragma("unroll")                                                       \
        for (int mi = 0; mi < 2; ++mi)                                          \
            s[mi] = *(const bf16x8*)(Pcur + (size_t)(t32) * 32768 + aoff[mi]);  \
    } while (0)

#define COMPUTE(buf, s)                                                         \
    do {                                                                        \
        bf16x8 bfr[4];                                                          \
        _Pragma("unroll")                                                       \
        for (int ni = 0; ni < 4; ++ni)                                          \
            bfr[ni] = *(const bf16x8*)(BsF + (buf) * 4096 + boff + ni * 512);   \
        _Pragma("unroll")                                                       \
        for (int mi = 0; mi < 2; ++mi)                                          \
            _Pragma("unroll")                                                   \
            for (int ni = 0; ni < 4; ++ni)                                      \
                acc[mi][ni] = __builtin_amdgcn_mfma_f32_16x16x32_bf16(          \
                    s[mi], bfr[ni], acc[mi][ni], 0, 0, 0);                      \
    } while (0)

    bf16x8 aA[2], aB[2];
    // prologue: tiles T0, T0+1 in flight (8 VMEM ops/thread)
    STAGE(0, T0);     LOADA(aA, T0);
    STAGE(1, T0 + 1); LOADA(aB, T0 + 1);

    int c0 = 0, c1 = 1, c2 = 2;
    for (int tp = 0; tp < 31; ++tp) {
        const int t = T0 + 2 * tp;
        // even slot: tile t (uses aA)
        asm volatile("s_waitcnt vmcnt(4)" ::: "memory");  // tile t landed
        __builtin_amdgcn_s_barrier();
        STAGE(c2, t + 2);
        COMPUTE(c0, aA);
        LOADA(aA, t + 2);
        { int z = c0; c0 = c1; c1 = c2; c2 = z; }
        // odd slot: tile t+1 (uses aB)
        asm volatile("s_waitcnt vmcnt(4)" ::: "memory");
        __builtin_amdgcn_s_barrier();
        STAGE(c2, t + 3);
        COMPUTE(c0, aB);
        LOADA(aB, t + 3);
        { int z = c0; c0 = c1; c1 = c2; c2 = z; }
    }
    // t = T0+62
    asm volatile("s_waitcnt vmcnt(4)" ::: "memory");
    __builtin_amdgcn_s_barrier();
    COMPUTE(c0, aA);
    { int z = c0; c0 = c1; c1 = c2; c2 = z; }
    // t = T0+63
    asm volatile("s_waitcnt vmcnt(0)" ::: "memory");
    __builtin_amdgcn_s_barrier();
    COMPUTE(c0, aB);
#undef STAGE
#undef LOADA
#undef COMPUTE

    // partial write, bf16. C/D: col=lane&15, row=(lane>>4)*4+reg.
    const int rowA0 = by * BM, rowB0 = bx * BN;
    unsigned short* D = Dp + (size_t)ks * HALF_ELEMS;
#pragma unroll
    for (int mi = 0; mi < 2; ++mi) {
        int i0 = rowA0 + m0 + mi * 16 + lk * 4;
#pragma unroll
        for (int ni = 0; ni < 4; ++ni) {
            int n = rowB0 + n0 + ni * 16 + lr;
#pragma unroll
            for (int r = 0; r < 4; ++r)
                D[(size_t)(i0 + r) * NODES + n] = f32_to_bf16(acc[mi][ni][r]);
        }
    }
}

// ---------------------------------------------------------------------------
// Kernel 4: combine partials + epilogue. Thread = (b, 8 consecutive m).
//   drive = (p0+p1) + x; hnew = 0.9h + 0.1(1-tanh(h)^2)drive
//   h <- hnew; Pnxt = pack(bf16(tanh(hnew))); out = hnew[c=0] (last step)
// ---------------------------------------------------------------------------
__global__ __launch_bounds__(256)
void combine_kernel(const unsigned short* __restrict__ Dp,
                    const float* __restrict__ x,
                    float* __restrict__ h,
                    unsigned short* __restrict__ Pnxt,
                    float* __restrict__ out) {
    int g  = blockIdx.x * 256 + threadIdx.x;   // 0..131071
    int b  = g >> 9;
    int mg = (g & 511) << 3;                   // m base (multiple of 8)
    size_t hbase = (size_t)b * DLEN + (size_t)mg * 4;

    f32x4 hv[8], xv[8];
#pragma unroll
    for (int e = 0; e < 8; ++e) {
        hv[e] = *(const f32x4*)(h + hbase + e * 4);
        xv[e] = *(const f32x4*)(x + hbase + e * 4);
    }
    u16x8 d0[4], d1[4];
#pragma unroll
    for (int c = 0; c < 4; ++c) {
        d0[c] = *(const u16x8*)(Dp + (size_t)(b * 4 + c) * NODES + mg);
        d1[c] = *(const u16x8*)(Dp + HALF_ELEMS + (size_t)(b * 4 + c) * NODES + mg);
    }
    u16x8 pn[4];
    float o[8];
#pragma unroll
    for (int e = 0; e < 8; ++e) {
#pragma unroll
        for (int c = 0; c < 4; ++c) {
            float p    = bf16_to_f32(d0[c][e]) + bf16_to_f32(d1[c][e]);
            float hvv  = hv[e][c];
            float rho  = tanhf(hvv);
            float drive = p + xv[e][c];
            float hnew = 0.9f * hvv + 0.1f * (1.0f - rho * rho) * drive;
            hv[e][c] = hnew;
            pn[c][e] = f32_to_bf16(tanhf(hnew));
            if (c == 0) o[e] = hnew;
        }
    }
#pragma unroll
    for (int e = 0; e < 8; ++e)
        *(f32x4*)(h + hbase + e * 4) = hv[e];
#pragma unroll
    for (int c = 0; c < 4; ++c) {
        size_t pa = (size_t)(mg >> 5) * 32768 + (size_t)(b >> 2) * 512
                  + (size_t)(((b & 3) * 4 + c) | (((mg >> 3) & 3) << 4)) * 8;
        *(u16x8*)(Pnxt + pa) = pn[c];
    }
    if (out) {
        *(f32x4*)(out + (size_t)b * NODES + mg)     = (f32x4){o[0], o[1], o[2], o[3]};
        *(f32x4*)(out + (size_t)b * NODES + mg + 4) = (f32x4){o[4], o[5], o[6], o[7]};
    }
}

// ---------------------------------------------------------------------------
extern "C" void kernel_launch(void* const* d_in, const int* in_sizes, int n_in,
                              void* d_out, int out_size, void* d_ws, size_t ws_size,
                              hipStream_t stream) {
    const float* x = (const float*)d_in[0];   // (256, 16384) f32
    const float* W = (const float*)d_in[1];   // (4096, 4096) f32
    float* out = (float*)d_out;               // (256, 4096) f32

    char* ws = (char*)d_ws;
    // ws: Wbp 32MB | P0 8MB | P1 8MB | h 16MB | Dp 16MB  (= 80 MB)
    unsigned short* Wbp = (unsigned short*)(ws);
    unsigned short* P0  = (unsigned short*)(ws + ((size_t)32 << 20));
    unsigned short* P1  = (unsigned short*)(ws + ((size_t)40 << 20));
    float*          h   = (float*)(ws + ((size_t)48 << 20));
    unsigned short* Dp  = (unsigned short*)(ws + ((size_t)64 << 20));

    symw_kernel<<<dim3(64, 64), 256, 0, stream>>>(W, Wbp);
    init_kernel<<<dim3(4096), 256, 0, stream>>>(x, h, P0);

    unsigned short* pc = P0;
    unsigned short* pn = P1;
    for (int s = 0; s < 10; ++s) {
        gemm_kernel<<<dim3(32, 16, 2), 256, 0, stream>>>(pc, Wbp, Dp);
        combine_kernel<<<dim3(512), 256, 0, stream>>>(
            Dp, x, h, pn, (s == 9) ? out : nullptr);
        unsigned short* t = pc; pc = pn; pn = t;
    }
}